// Round 2
// baseline (127.284 us; speedup 1.0000x reference)
//
#include <hip/hip_runtime.h>

#define SIGMA_C 1e-4f
#define EPS_C   1e-12f

struct V3 { float x, y, z; };

__device__ __forceinline__ V3 v3sub(V3 a, V3 b) { return {a.x - b.x, a.y - b.y, a.z - b.z}; }
__device__ __forceinline__ float v3dot(V3 a, V3 b) { return a.x * b.x + a.y * b.y + a.z * b.z; }
__device__ __forceinline__ V3 v3cross(V3 a, V3 b) {
    return {a.y * b.z - a.z * b.y,
            a.z * b.x - a.x * b.z,
            a.x * b.y - a.y * b.x};
}

__device__ __forceinline__ void tri_frame(const V3 v[3], V3& c, V3& n, float& r) {
    const float third = 1.0f / 3.0f;
    c.x = (v[0].x + v[1].x + v[2].x) * third;
    c.y = (v[0].y + v[1].y + v[2].y) * third;
    c.z = (v[0].z + v[1].z + v[2].z) * third;
    V3 e1 = v3sub(v[1], v[0]);
    V3 e2 = v3sub(v[2], v[0]);
    n = v3cross(e1, e2);
    float nn = sqrtf(v3dot(n, n));
    float inv = 1.0f / fmaxf(nn, EPS_C);
    n.x *= inv; n.y *= inv; n.z *= inv;
    V3 d0 = v3sub(v[0], c), d1 = v3sub(v[1], c), d2 = v3sub(v[2], c);
    float m = fmaxf(fmaxf(v3dot(d0, d0), v3dot(d1, d1)), v3dot(d2, d2));
    r = sqrtf(m);
}

__device__ __forceinline__ float cone_psi2(const V3 p[3], V3 c, V3 n, float r) {
    float inv_r = 1.0f / fmaxf(r, EPS_C);
    float s = 0.0f;
#pragma unroll
    for (int i = 0; i < 3; ++i) {
        V3 u = v3sub(p[i], c);
        float h = v3dot(u, n);
        V3 w = {u.x - h * n.x, u.y - h * n.y, u.z - h * n.z};
        float rho = sqrtf(v3dot(w, w));
        float radial = fmaxf(1.0f - rho * inv_r, 0.0f);
        float axial = fmaxf(SIGMA_C - h, 0.0f);   // PENALIZE_OUTSIDE = True
        float psi = radial * axial;
        s += psi * psi;
    }
    return s;
}

// ---------------- phase 1: per-(batch,face) 64-B record ----------------
// layout (16 floats): v0.xyz v1.xyz v2.xyz c.xyz n.xyz r
__global__ void precompute_tri(const float* __restrict__ verts,  // [B,V,3]
                               const int*   __restrict__ faces,  // [F,3]
                               float4* __restrict__ table,       // [B*F*4]
                               float* __restrict__ out,          // [B]
                               int V, int F, int B) {
    if (blockIdx.x == 0 && blockIdx.y == 0 && threadIdx.x < (unsigned)B)
        out[threadIdx.x] = 0.0f;

    const int f = blockIdx.x * blockDim.x + threadIdx.x;
    const int b = blockIdx.y;
    if (f >= F) return;

    const float* vb = verts + (size_t)b * (size_t)V * 3u;
    int i0 = faces[3 * f + 0];
    int i1 = faces[3 * f + 1];
    int i2 = faces[3 * f + 2];
    V3 v[3];
    v[0] = {vb[3 * i0 + 0], vb[3 * i0 + 1], vb[3 * i0 + 2]};
    v[1] = {vb[3 * i1 + 0], vb[3 * i1 + 1], vb[3 * i1 + 2]};
    v[2] = {vb[3 * i2 + 0], vb[3 * i2 + 1], vb[3 * i2 + 2]};
    V3 c, n; float r;
    tri_frame(v, c, n, r);

    float4* rec = table + ((size_t)b * F + f) * 4;
    rec[0] = {v[0].x, v[0].y, v[0].z, v[1].x};
    rec[1] = {v[1].y, v[1].z, v[2].x, v[2].y};
    rec[2] = {v[2].z, c.x, c.y, c.z};
    rec[3] = {n.x, n.y, n.z, r};
}

__device__ __forceinline__ void unpack(const float4 r0, const float4 r1,
                                       const float4 r2, const float4 r3,
                                       V3 p[3], V3& c, V3& n, float& r) {
    p[0] = {r0.x, r0.y, r0.z};
    p[1] = {r0.w, r1.x, r1.y};
    p[2] = {r1.z, r1.w, r2.x};
    c = {r2.y, r2.z, r2.w};
    n = {r3.x, r3.y, r3.z};
    r = r3.w;
}

// ---------------- phase 2: per-pair psi, reduce ----------------
__global__ void pair_kernel(const float4* __restrict__ table,  // [B*F*4]
                            const int2*  __restrict__ coll,    // [B,C]
                            float* __restrict__ out,           // [B]
                            int F, int C, int B) {
    const int b = blockIdx.x % B;          // batch -> XCD (round-robin heuristic)
    const int chunk = blockIdx.x / B;
    const int c = chunk * blockDim.x + threadIdx.x;

    float acc = 0.0f;
    if (c < C) {
        int2 idx = coll[(size_t)b * C + c];
        if ((idx.x | idx.y) >= 0) {
            const float4* R = table + ((size_t)b * F + idx.x) * 4;
            const float4* I = table + ((size_t)b * F + idx.y) * 4;
            float4 ra = R[0], rb_ = R[1], rc_ = R[2], rd = R[3];
            float4 ia = I[0], ib = I[1], ic_ = I[2], id_ = I[3];
            V3 rp[3], rcen, rn; float rr;
            unpack(ra, rb_, rc_, rd, rp, rcen, rn, rr);
            V3 ip[3], icen, inn; float ir;
            unpack(ia, ib, ic_, id_, ip, icen, inn, ir);
            acc  = cone_psi2(ip, rcen, rn, rr);   // psi_i
            acc += cone_psi2(rp, icen, inn, ir);  // psi_r
        }
    }

#pragma unroll
    for (int off = 32; off > 0; off >>= 1)
        acc += __shfl_down(acc, off, 64);

    __shared__ float red[16];
    int lane = threadIdx.x & 63;
    int wid  = threadIdx.x >> 6;
    if (lane == 0) red[wid] = acc;
    __syncthreads();
    if (threadIdx.x == 0) {
        float s = 0.0f;
        int nw = blockDim.x >> 6;
        for (int i = 0; i < nw; ++i) s += red[i];
        atomicAdd(&out[b], s);
    }
}

// ---------------- fallback (round-1 kernel) ----------------
__global__ void interp_zero(float* out, int n) {
    int i = blockIdx.x * blockDim.x + threadIdx.x;
    if (i < n) out[i] = 0.0f;
}

__global__ void pair_kernel_gather(const float* __restrict__ verts,
                                   const int*   __restrict__ faces,
                                   const int2*  __restrict__ coll,
                                   float* __restrict__ out,
                                   int V, int C) {
    const int b = blockIdx.y;
    const float* vb = verts + (size_t)b * (size_t)V * 3u;
    const int2* cb = coll + (size_t)b * (size_t)C;

    float acc = 0.0f;
    const int stride = gridDim.x * blockDim.x;
    for (int c = blockIdx.x * blockDim.x + threadIdx.x; c < C; c += stride) {
        int2 idx = cb[c];
        if ((idx.x | idx.y) >= 0) {
            const int* fr = faces + 3 * idx.x;
            const int* fi = faces + 3 * idx.y;
            V3 tr[3], ti[3];
#pragma unroll
            for (int j = 0; j < 3; ++j) {
                int vr = fr[j];
                tr[j] = {vb[3 * vr + 0], vb[3 * vr + 1], vb[3 * vr + 2]};
                int vi = fi[j];
                ti[j] = {vb[3 * vi + 0], vb[3 * vi + 1], vb[3 * vi + 2]};
            }
            V3 rc, rn; float rr;
            tri_frame(tr, rc, rn, rr);
            V3 ic, in_; float ir;
            tri_frame(ti, ic, in_, ir);
            acc += cone_psi2(ti, rc, rn, rr);
            acc += cone_psi2(tr, ic, in_, ir);
        }
    }

#pragma unroll
    for (int off = 32; off > 0; off >>= 1)
        acc += __shfl_down(acc, off, 64);

    __shared__ float red[16];
    int lane = threadIdx.x & 63;
    int wid  = threadIdx.x >> 6;
    if (lane == 0) red[wid] = acc;
    __syncthreads();
    if (threadIdx.x == 0) {
        float s = 0.0f;
        int nw = blockDim.x >> 6;
        for (int i = 0; i < nw; ++i) s += red[i];
        atomicAdd(&out[b], s);
    }
}

extern "C" void kernel_launch(void* const* d_in, const int* in_sizes, int n_in,
                              void* d_out, int out_size, void* d_ws, size_t ws_size,
                              hipStream_t stream) {
    const float* verts = (const float*)d_in[0];
    const int*   faces = (const int*)d_in[1];
    const int2*  coll  = (const int2*)d_in[2];
    float* out = (float*)d_out;

    const int B = out_size;                       // 8
    const int V = in_sizes[0] / (3 * B);          // 10475
    const int F = in_sizes[1] / 3;                // 20908
    const int C = in_sizes[2] / (2 * B);          // 262144

    const size_t table_bytes = (size_t)B * (size_t)F * 64u;

    if (ws_size >= table_bytes) {
        float4* table = (float4*)d_ws;

        dim3 pb(256);
        dim3 pg((F + 255) / 256, B);
        precompute_tri<<<pg, pb, 0, stream>>>(verts, faces, table, out, V, F, B);

        const int block = 256;
        const int chunks = (C + block - 1) / block;
        dim3 grid(chunks * B);
        pair_kernel<<<grid, block, 0, stream>>>(table, coll, out, F, C, B);
    } else {
        interp_zero<<<1, 64, 0, stream>>>(out, B);
        dim3 block(256);
        dim3 grid(256, B);
        pair_kernel_gather<<<grid, block, 0, stream>>>(verts, faces, coll, out, V, C);
    }
}

// Round 3
// 70.689 us; speedup vs baseline: 1.8006x; 1.8006x over previous
//
#include <hip/hip_runtime.h>

#define SIGMA_C 1e-4f
#define EPS_C   1e-12f
#define PAIRS_PER_THREAD 2

struct V3 { float x, y, z; };

__device__ __forceinline__ V3 v3sub(V3 a, V3 b) { return {a.x - b.x, a.y - b.y, a.z - b.z}; }
__device__ __forceinline__ float v3dot(V3 a, V3 b) { return a.x * b.x + a.y * b.y + a.z * b.z; }
__device__ __forceinline__ V3 v3cross(V3 a, V3 b) {
    return {a.y * b.z - a.z * b.y,
            a.z * b.x - a.x * b.z,
            a.x * b.y - a.y * b.x};
}

__device__ __forceinline__ void tri_frame(const V3 v[3], V3& c, V3& n, float& r) {
    const float third = 1.0f / 3.0f;
    c.x = (v[0].x + v[1].x + v[2].x) * third;
    c.y = (v[0].y + v[1].y + v[2].y) * third;
    c.z = (v[0].z + v[1].z + v[2].z) * third;
    V3 e1 = v3sub(v[1], v[0]);
    V3 e2 = v3sub(v[2], v[0]);
    n = v3cross(e1, e2);
    float nn = sqrtf(v3dot(n, n));
    float inv = 1.0f / fmaxf(nn, EPS_C);
    n.x *= inv; n.y *= inv; n.z *= inv;
    V3 d0 = v3sub(v[0], c), d1 = v3sub(v[1], c), d2 = v3sub(v[2], c);
    float m = fmaxf(fmaxf(v3dot(d0, d0), v3dot(d1, d1)), v3dot(d2, d2));
    r = sqrtf(m);
}

__device__ __forceinline__ float cone_psi2(const V3 p[3], V3 c, V3 n, float r) {
    float inv_r = 1.0f / fmaxf(r, EPS_C);
    float s = 0.0f;
#pragma unroll
    for (int i = 0; i < 3; ++i) {
        V3 u = v3sub(p[i], c);
        float h = v3dot(u, n);
        V3 w = {u.x - h * n.x, u.y - h * n.y, u.z - h * n.z};
        float rho = sqrtf(v3dot(w, w));
        float radial = fmaxf(1.0f - rho * inv_r, 0.0f);
        float axial = fmaxf(SIGMA_C - h, 0.0f);   // PENALIZE_OUTSIDE = True
        float psi = radial * axial;
        s += psi * psi;
    }
    return s;
}

// ---------------- phase 1: per-(batch,face) 64-B record ----------------
// layout (16 floats): v0.xyz v1.xyz v2.xyz c.xyz n.xyz r
// blockIdx.x % B == batch, so batch b's table slice is produced (and cached)
// on the same XCD that pair_kernel's %B mapping will read it from.
__global__ void precompute_tri(const float* __restrict__ verts,  // [B,V,3]
                               const int*   __restrict__ faces,  // [F,3]
                               float4* __restrict__ table,       // [B*F*4]
                               float* __restrict__ out,          // [B]
                               int V, int F, int B) {
    if (blockIdx.x == 0 && threadIdx.x < (unsigned)B)
        out[threadIdx.x] = 0.0f;

    const int b = blockIdx.x % B;
    const int chunk = blockIdx.x / B;
    const int f = chunk * blockDim.x + threadIdx.x;
    if (f >= F) return;

    const float* vb = verts + (size_t)b * (size_t)V * 3u;
    int i0 = faces[3 * f + 0];
    int i1 = faces[3 * f + 1];
    int i2 = faces[3 * f + 2];
    V3 v[3];
    v[0] = {vb[3 * i0 + 0], vb[3 * i0 + 1], vb[3 * i0 + 2]};
    v[1] = {vb[3 * i1 + 0], vb[3 * i1 + 1], vb[3 * i1 + 2]};
    v[2] = {vb[3 * i2 + 0], vb[3 * i2 + 1], vb[3 * i2 + 2]};
    V3 c, n; float r;
    tri_frame(v, c, n, r);

    float4* rec = table + ((size_t)b * F + f) * 4;
    rec[0] = {v[0].x, v[0].y, v[0].z, v[1].x};
    rec[1] = {v[1].y, v[1].z, v[2].x, v[2].y};
    rec[2] = {v[2].z, c.x, c.y, c.z};
    rec[3] = {n.x, n.y, n.z, r};
}

__device__ __forceinline__ void unpack(const float4 r0, const float4 r1,
                                       const float4 r2, const float4 r3,
                                       V3 p[3], V3& c, V3& n, float& r) {
    p[0] = {r0.x, r0.y, r0.z};
    p[1] = {r0.w, r1.x, r1.y};
    p[2] = {r1.z, r1.w, r2.x};
    c = {r2.y, r2.z, r2.w};
    n = {r3.x, r3.y, r3.z};
    r = r3.w;
}

// ---------------- phase 2: per-pair psi, reduce ----------------
__global__ void __launch_bounds__(256)
pair_kernel(const float4* __restrict__ table,  // [B*F*4]
            const int2*  __restrict__ coll,    // [B,C]
            float* __restrict__ out,           // [B]
            int F, int C, int B) {
    const int b = blockIdx.x % B;              // batch -> XCD pinning
    const int chunk = blockIdx.x / B;
    const int t = chunk * blockDim.x + threadIdx.x;
    const long long base = (long long)t * PAIRS_PER_THREAD;
    const int2* cb = coll + (size_t)b * C;
    const float4* tb = table + (size_t)b * F * 4;

    float acc = 0.0f;
    if (base < C) {
        int2 idx[PAIRS_PER_THREAD];
        if (base + PAIRS_PER_THREAD <= C) {
            // one coalesced 16-B load for 2 pairs
            int4 q = *reinterpret_cast<const int4*>(cb + base);
            idx[0] = {q.x, q.y};
            idx[1] = {q.z, q.w};
        } else {
#pragma unroll
            for (int j = 0; j < PAIRS_PER_THREAD; ++j)
                idx[j] = (base + j < C) ? cb[base + j] : make_int2(-1, -1);
        }

        // branchless: always gather (clamped to record 0), weight by validity.
        float w[PAIRS_PER_THREAD];
        float4 RG[PAIRS_PER_THREAD][4], IG[PAIRS_PER_THREAD][4];
#pragma unroll
        for (int j = 0; j < PAIRS_PER_THREAD; ++j) {
            w[j] = ((idx[j].x | idx[j].y) >= 0) ? 1.0f : 0.0f;
            const float4* R = tb + (size_t)max(idx[j].x, 0) * 4;
            const float4* I = tb + (size_t)max(idx[j].y, 0) * 4;
#pragma unroll
            for (int k = 0; k < 4; ++k) {
                RG[j][k] = R[k];
                IG[j][k] = I[k];
            }
        }
#pragma unroll
        for (int j = 0; j < PAIRS_PER_THREAD; ++j) {
            V3 rp[3], rcen, rn; float rr;
            unpack(RG[j][0], RG[j][1], RG[j][2], RG[j][3], rp, rcen, rn, rr);
            V3 ip[3], icen, inn; float ir;
            unpack(IG[j][0], IG[j][1], IG[j][2], IG[j][3], ip, icen, inn, ir);
            acc += w[j] * (cone_psi2(ip, rcen, rn, rr) + cone_psi2(rp, icen, inn, ir));
        }
    }

#pragma unroll
    for (int off = 32; off > 0; off >>= 1)
        acc += __shfl_down(acc, off, 64);

    __shared__ float red[16];
    int lane = threadIdx.x & 63;
    int wid  = threadIdx.x >> 6;
    if (lane == 0) red[wid] = acc;
    __syncthreads();
    if (threadIdx.x == 0) {
        float s = 0.0f;
        int nw = blockDim.x >> 6;
        for (int i = 0; i < nw; ++i) s += red[i];
        atomicAdd(&out[b], s);
    }
}

// ---------------- fallback (round-1 kernel, table doesn't fit ws) ----------------
__global__ void interp_zero(float* out, int n) {
    int i = blockIdx.x * blockDim.x + threadIdx.x;
    if (i < n) out[i] = 0.0f;
}

__global__ void pair_kernel_gather(const float* __restrict__ verts,
                                   const int*   __restrict__ faces,
                                   const int2*  __restrict__ coll,
                                   float* __restrict__ out,
                                   int V, int C) {
    const int b = blockIdx.y;
    const float* vb = verts + (size_t)b * (size_t)V * 3u;
    const int2* cb = coll + (size_t)b * (size_t)C;

    float acc = 0.0f;
    const int stride = gridDim.x * blockDim.x;
    for (int c = blockIdx.x * blockDim.x + threadIdx.x; c < C; c += stride) {
        int2 idx = cb[c];
        if ((idx.x | idx.y) >= 0) {
            const int* fr = faces + 3 * idx.x;
            const int* fi = faces + 3 * idx.y;
            V3 tr[3], ti[3];
#pragma unroll
            for (int j = 0; j < 3; ++j) {
                int vr = fr[j];
                tr[j] = {vb[3 * vr + 0], vb[3 * vr + 1], vb[3 * vr + 2]};
                int vi = fi[j];
                ti[j] = {vb[3 * vi + 0], vb[3 * vi + 1], vb[3 * vi + 2]};
            }
            V3 rc, rn; float rr;
            tri_frame(tr, rc, rn, rr);
            V3 ic, in_; float ir;
            tri_frame(ti, ic, in_, ir);
            acc += cone_psi2(ti, rc, rn, rr);
            acc += cone_psi2(tr, ic, in_, ir);
        }
    }

#pragma unroll
    for (int off = 32; off > 0; off >>= 1)
        acc += __shfl_down(acc, off, 64);

    __shared__ float red[16];
    int lane = threadIdx.x & 63;
    int wid  = threadIdx.x >> 6;
    if (lane == 0) red[wid] = acc;
    __syncthreads();
    if (threadIdx.x == 0) {
        float s = 0.0f;
        int nw = blockDim.x >> 6;
        for (int i = 0; i < nw; ++i) s += red[i];
        atomicAdd(&out[b], s);
    }
}

extern "C" void kernel_launch(void* const* d_in, const int* in_sizes, int n_in,
                              void* d_out, int out_size, void* d_ws, size_t ws_size,
                              hipStream_t stream) {
    const float* verts = (const float*)d_in[0];
    const int*   faces = (const int*)d_in[1];
    const int2*  coll  = (const int2*)d_in[2];
    float* out = (float*)d_out;

    const int B = out_size;                       // 8
    const int V = in_sizes[0] / (3 * B);          // 10475
    const int F = in_sizes[1] / 3;                // 20908
    const int C = in_sizes[2] / (2 * B);          // 262144

    const size_t table_bytes = (size_t)B * (size_t)F * 64u;

    if (ws_size >= table_bytes) {
        float4* table = (float4*)d_ws;

        const int pchunks = (F + 255) / 256;
        precompute_tri<<<dim3(pchunks * B), dim3(256), 0, stream>>>(
            verts, faces, table, out, V, F, B);

        const int block = 256;
        const int per_block = block * PAIRS_PER_THREAD;
        const int chunks = (C + per_block - 1) / per_block;
        pair_kernel<<<dim3(chunks * B), dim3(block), 0, stream>>>(
            table, coll, out, F, C, B);
    } else {
        interp_zero<<<1, 64, 0, stream>>>(out, B);
        pair_kernel_gather<<<dim3(256, B), dim3(256), 0, stream>>>(
            verts, faces, coll, out, V, C);
    }
}

// Round 4
// 32.165 us; speedup vs baseline: 3.9572x; 2.1977x over previous
//
#include <hip/hip_runtime.h>
#include <hip/hip_fp16.h>

#define SIGMA_C 1e-4f
#define EPS_C   1e-12f
#define BLOCK   256
#define GPT     4          // int4 groups per thread, 2 pairs per group

struct V3 { float x, y, z; };

__device__ __forceinline__ V3 v3sub(V3 a, V3 b) { return {a.x - b.x, a.y - b.y, a.z - b.z}; }
__device__ __forceinline__ float v3dot(V3 a, V3 b) { return a.x * b.x + a.y * b.y + a.z * b.z; }
__device__ __forceinline__ V3 v3cross(V3 a, V3 b) {
    return {a.y * b.z - a.z * b.y,
            a.z * b.x - a.x * b.z,
            a.x * b.y - a.y * b.x};
}
__device__ __forceinline__ int imax0(int x) { return x > 0 ? x : 0; }

__device__ __forceinline__ void tri_frame(const V3 v[3], V3& c, V3& n, float& r) {
    const float third = 1.0f / 3.0f;
    c.x = (v[0].x + v[1].x + v[2].x) * third;
    c.y = (v[0].y + v[1].y + v[2].y) * third;
    c.z = (v[0].z + v[1].z + v[2].z) * third;
    V3 e1 = v3sub(v[1], v[0]);
    V3 e2 = v3sub(v[2], v[0]);
    n = v3cross(e1, e2);
    float nn = sqrtf(v3dot(n, n));
    float inv = 1.0f / fmaxf(nn, EPS_C);
    n.x *= inv; n.y *= inv; n.z *= inv;
    V3 d0 = v3sub(v[0], c), d1 = v3sub(v[1], c), d2 = v3sub(v[2], c);
    float m = fmaxf(fmaxf(v3dot(d0, d0), v3dot(d1, d1)), v3dot(d2, d2));
    r = sqrtf(m);
}

__device__ __forceinline__ float cone_psi2(const V3 p[3], V3 c, V3 n, float r) {
    float inv_r = 1.0f / fmaxf(r, EPS_C);
    float s = 0.0f;
#pragma unroll
    for (int i = 0; i < 3; ++i) {
        V3 u = v3sub(p[i], c);
        float h = v3dot(u, n);
        V3 w = {u.x - h * n.x, u.y - h * n.y, u.z - h * n.z};
        float rho = sqrtf(v3dot(w, w));
        float radial = fmaxf(1.0f - rho * inv_r, 0.0f);
        float axial = fmaxf(SIGMA_C - h, 0.0f);   // PENALIZE_OUTSIDE = True
        float psi = radial * axial;
        s += psi * psi;
    }
    return s;
}

// fp16 record: 16 halves = 32 B = 2 x float4
// h[0..2]=v0 h[3..5]=v1 h[6..8]=v2 h[9..11]=c h[12..14]=n h[15]=r
union RecU { float4 f[2]; __half h[16]; };

// ---------------- phase 1: per-(batch,face) 32-B fp16 record ----------------
__global__ void precompute_tri_h(const float* __restrict__ verts,  // [B,V,3]
                                 const int*   __restrict__ faces,  // [F,3]
                                 float4* __restrict__ table,       // [B*F*2]
                                 float* __restrict__ out,          // [B]
                                 int V, int F, int B) {
    if (blockIdx.x == 0 && threadIdx.x < (unsigned)B)
        out[threadIdx.x] = 0.0f;

    const int b = blockIdx.x % B;      // batch -> XCD co-location with pair kernel
    const int chunk = blockIdx.x / B;
    const int f = chunk * blockDim.x + threadIdx.x;
    if (f >= F) return;

    const float* vb = verts + (size_t)b * (size_t)V * 3u;
    int i0 = faces[3 * f + 0];
    int i1 = faces[3 * f + 1];
    int i2 = faces[3 * f + 2];
    V3 v[3];
    v[0] = {vb[3 * i0 + 0], vb[3 * i0 + 1], vb[3 * i0 + 2]};
    v[1] = {vb[3 * i1 + 0], vb[3 * i1 + 1], vb[3 * i1 + 2]};
    v[2] = {vb[3 * i2 + 0], vb[3 * i2 + 1], vb[3 * i2 + 2]};
    V3 c, n; float r;
    tri_frame(v, c, n, r);

    RecU u;
    u.h[0]  = __float2half(v[0].x); u.h[1]  = __float2half(v[0].y); u.h[2]  = __float2half(v[0].z);
    u.h[3]  = __float2half(v[1].x); u.h[4]  = __float2half(v[1].y); u.h[5]  = __float2half(v[1].z);
    u.h[6]  = __float2half(v[2].x); u.h[7]  = __float2half(v[2].y); u.h[8]  = __float2half(v[2].z);
    u.h[9]  = __float2half(c.x);    u.h[10] = __float2half(c.y);    u.h[11] = __float2half(c.z);
    u.h[12] = __float2half(n.x);    u.h[13] = __float2half(n.y);    u.h[14] = __float2half(n.z);
    u.h[15] = __float2half(r);

    float4* rec = table + ((size_t)b * F + f) * 2;
    rec[0] = u.f[0];
    rec[1] = u.f[1];
}

__device__ __forceinline__ void unpack_rec_h(float4 a, float4 b,
                                             V3 p[3], V3& c, V3& n, float& r) {
    RecU u; u.f[0] = a; u.f[1] = b;
    p[0] = {__half2float(u.h[0]),  __half2float(u.h[1]),  __half2float(u.h[2])};
    p[1] = {__half2float(u.h[3]),  __half2float(u.h[4]),  __half2float(u.h[5])};
    p[2] = {__half2float(u.h[6]),  __half2float(u.h[7]),  __half2float(u.h[8])};
    c = {__half2float(u.h[9]),  __half2float(u.h[10]), __half2float(u.h[11])};
    n = {__half2float(u.h[12]), __half2float(u.h[13]), __half2float(u.h[14])};
    r = __half2float(u.h[15]);
}

// gather 4 triangle records (2 pairs) — 8 independent float4 loads
__device__ __forceinline__ void gather_group(const float4* __restrict__ tb, int4 q,
                                             float4 G[8], float w[2]) {
    w[0] = ((q.x | q.y) >= 0) ? 1.0f : 0.0f;
    w[1] = ((q.z | q.w) >= 0) ? 1.0f : 0.0f;
    const float4* R0 = tb + (size_t)imax0(q.x) * 2;
    const float4* I0 = tb + (size_t)imax0(q.y) * 2;
    const float4* R1 = tb + (size_t)imax0(q.z) * 2;
    const float4* I1 = tb + (size_t)imax0(q.w) * 2;
    G[0] = R0[0]; G[1] = R0[1];
    G[2] = I0[0]; G[3] = I0[1];
    G[4] = R1[0]; G[5] = R1[1];
    G[6] = I1[0]; G[7] = I1[1];
}

__device__ __forceinline__ float compute_pair(const float4 G0, const float4 G1,
                                              const float4 G2, const float4 G3, float w) {
    V3 rp[3], rc, rn; float rr;
    unpack_rec_h(G0, G1, rp, rc, rn, rr);
    V3 ip[3], ic, inn; float ir;
    unpack_rec_h(G2, G3, ip, ic, inn, ir);
    return w * (cone_psi2(ip, rc, rn, rr) + cone_psi2(rp, ic, inn, ir));
}

__device__ __forceinline__ float compute_group(const float4 G[8], const float w[2]) {
    return compute_pair(G[0], G[1], G[2], G[3], w[0]) +
           compute_pair(G[4], G[5], G[6], G[7], w[1]);
}

// ---------------- phase 2: depth-2 pipelined pair kernel ----------------
__global__ void __launch_bounds__(BLOCK)
pair_kernel_h(const float4* __restrict__ table,  // [B*F*2]
              const int4*  __restrict__ coll4,   // [B*C4]
              float* __restrict__ out,           // [B]
              int F, int C4, int B) {
    const int b = blockIdx.x % B;                // batch -> XCD pinning
    const int chunk = blockIdx.x / B;
    const int4* cb = coll4 + (size_t)b * C4;
    const float4* tb = table + (size_t)b * ((size_t)F * 2);

    const int base = chunk * (BLOCK * GPT) + threadIdx.x;

    float acc = 0.0f;
    float4 GA[8], GB[8];
    float wA[2], wB[2];
    int4 q_even, q_odd;

    {   // prologue: q for groups 0 and 1; gather group 0
        int g0 = base;
        int g1 = base + BLOCK;
        q_even = (g0 < C4) ? cb[g0] : make_int4(-1, -1, -1, -1);
        q_odd  = (GPT > 1 && g1 < C4) ? cb[g1] : make_int4(-1, -1, -1, -1);
        gather_group(tb, q_even, GA, wA);
    }

#pragma unroll
    for (int i = 0; i < GPT; ++i) {
        if ((i & 1) == 0) {
            if (i + 2 < GPT) {                     // prefetch q for group i+2
                int g = base + (i + 2) * BLOCK;
                q_even = (g < C4) ? cb[g] : make_int4(-1, -1, -1, -1);
            }
            if (i + 1 < GPT)                       // prefetch records for group i+1
                gather_group(tb, q_odd, GB, wB);
            acc += compute_group(GA, wA);
        } else {
            if (i + 2 < GPT) {
                int g = base + (i + 2) * BLOCK;
                q_odd = (g < C4) ? cb[g] : make_int4(-1, -1, -1, -1);
            }
            if (i + 1 < GPT)
                gather_group(tb, q_even, GA, wA);
            acc += compute_group(GB, wB);
        }
    }

    // wave (64) shuffle reduction
#pragma unroll
    for (int off = 32; off > 0; off >>= 1)
        acc += __shfl_down(acc, off, 64);

    __shared__ float red[16];
    int lane = threadIdx.x & 63;
    int wid  = threadIdx.x >> 6;
    if (lane == 0) red[wid] = acc;
    __syncthreads();
    if (threadIdx.x == 0) {
        float s = 0.0f;
        int nw = blockDim.x >> 6;
        for (int i = 0; i < nw; ++i) s += red[i];
        atomicAdd(&out[b], s);
    }
}

// ---------------- fallback (direct gather, fp32) ----------------
__global__ void interp_zero(float* out, int n) {
    int i = blockIdx.x * blockDim.x + threadIdx.x;
    if (i < n) out[i] = 0.0f;
}

__global__ void pair_kernel_gather(const float* __restrict__ verts,
                                   const int*   __restrict__ faces,
                                   const int2*  __restrict__ coll,
                                   float* __restrict__ out,
                                   int V, int C) {
    const int b = blockIdx.y;
    const float* vb = verts + (size_t)b * (size_t)V * 3u;
    const int2* cb = coll + (size_t)b * (size_t)C;

    float acc = 0.0f;
    const int stride = gridDim.x * blockDim.x;
    for (int c = blockIdx.x * blockDim.x + threadIdx.x; c < C; c += stride) {
        int2 idx = cb[c];
        if ((idx.x | idx.y) >= 0) {
            const int* fr = faces + 3 * idx.x;
            const int* fi = faces + 3 * idx.y;
            V3 tr[3], ti[3];
#pragma unroll
            for (int j = 0; j < 3; ++j) {
                int vr = fr[j];
                tr[j] = {vb[3 * vr + 0], vb[3 * vr + 1], vb[3 * vr + 2]};
                int vi = fi[j];
                ti[j] = {vb[3 * vi + 0], vb[3 * vi + 1], vb[3 * vi + 2]};
            }
            V3 rc, rn; float rr;
            tri_frame(tr, rc, rn, rr);
            V3 ic, in_; float ir;
            tri_frame(ti, ic, in_, ir);
            acc += cone_psi2(ti, rc, rn, rr);
            acc += cone_psi2(tr, ic, in_, ir);
        }
    }

#pragma unroll
    for (int off = 32; off > 0; off >>= 1)
        acc += __shfl_down(acc, off, 64);

    __shared__ float red[16];
    int lane = threadIdx.x & 63;
    int wid  = threadIdx.x >> 6;
    if (lane == 0) red[wid] = acc;
    __syncthreads();
    if (threadIdx.x == 0) {
        float s = 0.0f;
        int nw = blockDim.x >> 6;
        for (int i = 0; i < nw; ++i) s += red[i];
        atomicAdd(&out[b], s);
    }
}

extern "C" void kernel_launch(void* const* d_in, const int* in_sizes, int n_in,
                              void* d_out, int out_size, void* d_ws, size_t ws_size,
                              hipStream_t stream) {
    const float* verts = (const float*)d_in[0];
    const int*   faces = (const int*)d_in[1];
    float* out = (float*)d_out;

    const int B = out_size;                       // 8
    const int V = in_sizes[0] / (3 * B);          // 10475
    const int F = in_sizes[1] / 3;                // 20908
    const int C = in_sizes[2] / (2 * B);          // 262144

    const size_t table_bytes = (size_t)B * (size_t)F * 32u;

    if (ws_size >= table_bytes && (C % 2) == 0) {
        float4* table = (float4*)d_ws;
        const int4* coll4 = (const int4*)d_in[2];
        const int C4 = C / 2;

        const int pchunks = (F + 255) / 256;
        precompute_tri_h<<<dim3(pchunks * B), dim3(256), 0, stream>>>(
            verts, faces, table, out, V, F, B);

        const int per_block = BLOCK * GPT;                 // int4 groups per block
        const int chunks = (C4 + per_block - 1) / per_block;
        pair_kernel_h<<<dim3(chunks * B), dim3(BLOCK), 0, stream>>>(
            table, coll4, out, F, C4, B);
    } else {
        const int2* coll = (const int2*)d_in[2];
        interp_zero<<<1, 64, 0, stream>>>(out, B);
        pair_kernel_gather<<<dim3(256, B), dim3(256), 0, stream>>>(
            verts, faces, coll, out, V, C);
    }
}